// Round 2
// baseline (156.029 us; speedup 1.0000x reference)
//
#include <hip/hip_runtime.h>
#include <hip/hip_bf16.h>

// out[b,t] = cumsum_t( relu(x @ Wh^T + bh) ) + (x @ Wb + bb)
// B=16384, D=1024, T=512. fp32 in/out; GEMM done in bf16 MFMA (fp32 accum).
// R2: BK 64->32 => LDS 145.5KB -> 73.3KB => 2 blocks/CU, 4 waves/SIMD.
//     Cross-block overlap hides the per-iter barrier drain that was 85% of R1.

typedef __bf16 bf16x8 __attribute__((ext_vector_type(8)));
typedef __bf16 bf16x4 __attribute__((ext_vector_type(4)));
typedef float f32x4 __attribute__((ext_vector_type(4)));

typedef const __attribute__((address_space(1))) void* gas_cptr;
typedef __attribute__((address_space(3))) void* las_ptr;

#define BM 64
#define BK 32     // elements; 64 bytes per row in LDS
#define NKIT 32   // 1024 / 32
#define TDIM 512
#define DDIM 1024

// ---- kernel 1: Wh fp32 -> bf16 (512x1024 = 524288 elems, 4/thread) ----
__global__ __launch_bounds__(256) void cvt_wh_kernel(const float* __restrict__ src,
                                                     __bf16* __restrict__ dst) {
    const int i = (blockIdx.x * 256 + threadIdx.x) * 4;
    const float4 v = *reinterpret_cast<const float4*>(src + i);
    bf16x4 o;
    o[0] = (__bf16)v.x; o[1] = (__bf16)v.y; o[2] = (__bf16)v.z; o[3] = (__bf16)v.w;
    *reinterpret_cast<bf16x4*>(dst + i) = o;
}

// swizzle: byte ^= ((row>>1)&3)<<4  -- makes the quarter-wave b128 pattern
// (16 rows x 64B, same 16B slot) hit all 8 bank-groups 2-way (free).
__device__ __forceinline__ int swz(int row) { return ((row >> 1) & 3) << 4; }

// ---- kernel 2: fused GEMM + bias + relu + row-cumsum + base add ----
__global__ __launch_bounds__(512, 4) void survival_kernel(
    const float* __restrict__ x,      // [16384][1024] fp32
    const __bf16* __restrict__ Whb,   // [512][1024] bf16 (pre-converted)
    const float* __restrict__ bh,     // [512]
    const float* __restrict__ Wb,     // [1024]
    const float* __restrict__ bbp,    // [1]
    float* __restrict__ out)          // [16384][512] fp32
{
    __shared__ __align__(16) char Alds[2][BM * 64];       // 8 KB
    __shared__ __align__(16) char Blds[2][TDIM * 64];     // 64 KB
    __shared__ float baseLds[BM];
    __shared__ float totLds[BM][4];

    const int tid  = threadIdx.x;
    const int lane = tid & 63;
    const int wid  = tid >> 6;   // 0..7
    const int wm   = wid >> 2;   // 0..1  (row half: 32 rows)
    const int wn   = wid & 3;    // 0..3  (col quarter: 128 cols)
    const int brow = blockIdx.x * BM;

    const float bb0 = bbp[0];

    // --- A staging map: thread -> (row ar, 4-elem k chunk) ---
    const int ar = tid >> 3;            // 0..63
    const int au = tid & 7;             // 8B unit within 64B row
    const float* xrow  = x  + (size_t)(brow + ar) * DDIM + au * 4;
    const float* wbrow = Wb + au * 4;
    char* const a_dst0 = &Alds[0][0] + ar * 64 + ((au * 8) ^ swz(ar));

    // --- B staging map: per wave 4 global_load_lds of 1 KB (16 rows each) ---
    const int b_row0 = wid * 64 + (lane >> 2);   // + c*16
    const int b_slot = lane & 3;

    float bpart = 0.f;
    f32x4 acc[2][8];
#pragma unroll
    for (int rt = 0; rt < 2; ++rt)
#pragma unroll
        for (int n = 0; n < 8; ++n)
            acc[rt][n] = (f32x4){0.f, 0.f, 0.f, 0.f};

    auto stage = [&](int buf, int it) {
        const int k0 = it * BK;
        // B tiles: linear LDS dest, inverse-swizzled global source (rule #21)
#pragma unroll
        for (int c = 0; c < 4; ++c) {
            const int row  = b_row0 + c * 16;
            const int colb = (b_slot * 16) ^ swz(row);            // byte in 64B row
            const __bf16* g = Whb + (size_t)row * DDIM + k0 + (colb >> 1);
            char* l = &Blds[buf][0] + (wid * 64 + c * 16) * 64;   // wave-uniform base
            __builtin_amdgcn_global_load_lds((gas_cptr)(const void*)g,
                                             (las_ptr)(void*)l, 16, 0, 0);
        }
        // A tile: fp32 load, fused base-dot, convert, swizzled ds_write_b64
        const float4 xv = *reinterpret_cast<const float4*>(xrow + k0);
        const float4 wv = *reinterpret_cast<const float4*>(wbrow + k0);
        bpart += xv.x * wv.x + xv.y * wv.y + xv.z * wv.z + xv.w * wv.w;
        bf16x4 av;
        av[0] = (__bf16)xv.x; av[1] = (__bf16)xv.y; av[2] = (__bf16)xv.z; av[3] = (__bf16)xv.w;
        *reinterpret_cast<bf16x4*>(a_dst0 + buf * (BM * 64)) = av;
    };

    auto compute = [&](int buf) {
        const char* Ab = &Blds[0][0];  // placeholder to silence unused warnings
        (void)Ab;
        const char* Abuf = &Alds[buf][0];
        const char* Bbuf = &Blds[buf][0];
        const int slot = (lane >> 4) * 16;   // 16B slot within 64B row
        bf16x8 af[2];
#pragma unroll
        for (int rt = 0; rt < 2; ++rt) {
            const int row = wm * 32 + rt * 16 + (lane & 15);
            af[rt] = *reinterpret_cast<const bf16x8*>(Abuf + row * 64 + (slot ^ swz(row)));
        }
#pragma unroll
        for (int n = 0; n < 8; ++n) {
            const int trow = wn * 128 + n * 16 + (lane & 15);
            const bf16x8 bfr = *reinterpret_cast<const bf16x8*>(
                Bbuf + trow * 64 + (slot ^ swz(trow)));
            acc[0][n] = __builtin_amdgcn_mfma_f32_16x16x32_bf16(af[0], bfr, acc[0][n], 0, 0, 0);
            acc[1][n] = __builtin_amdgcn_mfma_f32_16x16x32_bf16(af[1], bfr, acc[1][n], 0, 0, 0);
        }
    };

    // --- K loop: double-buffered, one barrier per iter ---
    stage(0, 0);
    __syncthreads();
#pragma unroll 2
    for (int it = 0; it < NKIT; ++it) {
        const int cur = it & 1;
        if (it + 1 < NKIT) stage(cur ^ 1, it + 1);
        compute(cur);
        __syncthreads();
    }

    // --- base = x@Wb + bb : reduce 8 partials per row (same-wave contiguous) ---
    bpart += __shfl_xor(bpart, 1, 8);
    bpart += __shfl_xor(bpart, 2, 8);
    bpart += __shfl_xor(bpart, 4, 8);
    if ((tid & 7) == 0) baseLds[tid >> 3] = bpart + bb0;

    // --- epilogue: bias + relu + in-register inclusive scan over columns ---
    // C layout (m89): col = lane&15, row = (lane>>4)*4 + j  within each 16x16 tile
    float bhv[8];
#pragma unroll
    for (int n = 0; n < 8; ++n)
        bhv[n] = bh[wn * 128 + n * 16 + (lane & 15)];

    float carry[2][4] = {{0.f, 0.f, 0.f, 0.f}, {0.f, 0.f, 0.f, 0.f}};
#pragma unroll
    for (int n = 0; n < 8; ++n) {
#pragma unroll
        for (int rt = 0; rt < 2; ++rt) {
#pragma unroll
            for (int j = 0; j < 4; ++j) {
                float v = fmaxf(acc[rt][n][j] + bhv[n], 0.f);
                // inclusive scan across the 16-lane column segment
#pragma unroll
                for (int off = 1; off < 16; off <<= 1) {
                    const float u = __shfl_up(v, (unsigned)off, 16);
                    if ((lane & 15) >= off) v += u;
                }
                v += carry[rt][j];
                carry[rt][j] = __shfl(v, 15, 16);  // running row total
                acc[rt][n][j] = v;
            }
        }
    }

    // per-row 128-col chunk totals -> LDS for cross-wave carry
    if ((lane & 15) == 0) {
#pragma unroll
        for (int rt = 0; rt < 2; ++rt)
#pragma unroll
            for (int j = 0; j < 4; ++j) {
                const int r = wm * 32 + rt * 16 + (lane >> 4) * 4 + j;
                totLds[r][wn] = carry[rt][j];
            }
    }
    __syncthreads();

#pragma unroll
    for (int rt = 0; rt < 2; ++rt) {
#pragma unroll
        for (int j = 0; j < 4; ++j) {
            const int r = wm * 32 + rt * 16 + (lane >> 4) * 4 + j;
            float rc = baseLds[r];
            if (wn > 0) rc += totLds[r][0];
            if (wn > 1) rc += totLds[r][1];
            if (wn > 2) rc += totLds[r][2];
            float* orow = out + (size_t)(brow + r) * TDIM + wn * 128 + (lane & 15);
#pragma unroll
            for (int n = 0; n < 8; ++n)
                orow[n * 16] = acc[rt][n][j] + rc;
        }
    }
}

extern "C" void kernel_launch(void* const* d_in, const int* in_sizes, int n_in,
                              void* d_out, int out_size, void* d_ws, size_t ws_size,
                              hipStream_t stream) {
    const float* x  = (const float*)d_in[0];  // [16384][1024]
    const float* Wh = (const float*)d_in[1];  // [512][1024]
    const float* bh = (const float*)d_in[2];  // [512]
    const float* Wb = (const float*)d_in[3];  // [1024]
    const float* bb = (const float*)d_in[4];  // [1]
    float* out = (float*)d_out;               // [16384][512]
    __bf16* Whb = (__bf16*)d_ws;              // 1 MB scratch

    cvt_wh_kernel<<<512, 256, 0, stream>>>(Wh, Whb);
    survival_kernel<<<256, 512, 0, stream>>>(x, Whb, bh, Wb, bb, out);
}

// Round 3
// 134.638 us; speedup vs baseline: 1.1589x; 1.1589x over previous
//
#include <hip/hip_runtime.h>
#include <hip/hip_bf16.h>

// out[b,t] = cumsum_t( relu(x @ Wh^T + bh) ) + (x @ Wb + bb)
// B=16384, D=1024, T=512. fp32 in/out; GEMM in bf16 MFMA (fp32 accum).
// R3: grid=256 means 1 block/CU ALWAYS -> raise waves/block to 16 (1024 thr)
//     and replace __syncthreads with raw s_barrier + counted vmcnt(6) so
//     next-tile DMA stays in flight across barriers (T3/T4-lite).

typedef __bf16 bf16x8 __attribute__((ext_vector_type(8)));
typedef __bf16 bf16x4 __attribute__((ext_vector_type(4)));
typedef float f32x4 __attribute__((ext_vector_type(4)));

typedef const __attribute__((address_space(1))) void* gas_cptr;
typedef __attribute__((address_space(3))) void* las_ptr;

#define BM 64
#define BK 64     // elements; 128 B per LDS row
#define NKIT 16   // 1024/64
#define TDIM 512
#define DDIM 1024
#define ASZ (BM * 128)
#define BSZ (TDIM * 128)

#define WAIT_TOP()  asm volatile("s_waitcnt vmcnt(6) lgkmcnt(0)" ::: "memory")
#define WAIT_LGKM() asm volatile("s_waitcnt lgkmcnt(0)" ::: "memory")
#define WAIT_VM0()  asm volatile("s_waitcnt vmcnt(0)" ::: "memory")
#define SBAR()      __builtin_amdgcn_s_barrier()

// ---- kernel 1: Wh fp32 -> bf16 ----
__global__ __launch_bounds__(256) void cvt_wh_kernel(const float* __restrict__ src,
                                                     __bf16* __restrict__ dst) {
    const int i = (blockIdx.x * 256 + threadIdx.x) * 4;
    const float4 v = *reinterpret_cast<const float4*>(src + i);
    bf16x4 o;
    o[0] = (__bf16)v.x; o[1] = (__bf16)v.y; o[2] = (__bf16)v.z; o[3] = (__bf16)v.w;
    *reinterpret_cast<bf16x4*>(dst + i) = o;
}

// XOR-swizzle of the 16B granule within a 128B row (verified conflict-free in R1)
__device__ __forceinline__ int swz(int row) { return ((row >> 1) & 7) << 4; }

// ---- kernel 2: fused GEMM + bias + relu + row-cumsum + base ----
__global__ __launch_bounds__(1024, 4) void survival_kernel(
    const float* __restrict__ x,      // [16384][1024] fp32
    const __bf16* __restrict__ Whb,   // [512][1024] bf16
    const float* __restrict__ bh,     // [512]
    const float* __restrict__ Wb,     // [1024]
    const float* __restrict__ bbp,    // [1]
    float* __restrict__ out)          // [16384][512] fp32
{
    __shared__ __align__(16) char Alds[2][ASZ];   // 16 KB
    __shared__ __align__(16) char Blds[2][BSZ];   // 128 KB
    __shared__ float baseLds[BM];
    __shared__ float totLds[BM][8];

    const int tid  = threadIdx.x;
    const int lane = tid & 63;
    const int wid  = tid >> 6;   // 0..15
    const int wm   = wid >> 3;   // 0..1  (row half: 32 rows)
    const int wn   = wid & 7;    // 0..7  (col eighth: 64 cols)
    const int brow = blockIdx.x * BM;

    const float bb0 = bbp[0];

    // --- A staging map: thread -> (row ar, 4-elem chunk ac) ---
    const int ar = tid >> 4;            // 0..63
    const int ac = tid & 15;            // chunk of 4 fp32 (8B as bf16)
    const float* xrow  = x  + (size_t)(brow + ar) * DDIM + ac * 4;
    const float* wbrow = Wb + ac * 4;
    char* const a_dst0 = &Alds[0][0] + ar * 128 + ((ac * 8) ^ swz(ar));

    // --- B staging map: 16 waves x 32 rows; 4 DMA of 1KB (8 rows) each ---
    const int b_row0 = wid * 32 + (lane >> 3);
    const int b_slot = lane & 7;

    float bpart = 0.f;
    f32x4 acc[2][4];
#pragma unroll
    for (int rt = 0; rt < 2; ++rt)
#pragma unroll
        for (int n = 0; n < 4; ++n)
            acc[rt][n] = (f32x4){0.f, 0.f, 0.f, 0.f};

    float4 xv, wv;

    auto stage_issue = [&](int buf, int it) {
        const int k0 = it * BK;
        xv = *reinterpret_cast<const float4*>(xrow + k0);    // 1 vm op
        wv = *reinterpret_cast<const float4*>(wbrow + k0);   // 1 vm op
#pragma unroll
        for (int c = 0; c < 4; ++c) {                        // 4 vm ops
            const int row  = b_row0 + c * 8;
            const int colb = (b_slot * 16) ^ swz(row);
            const __bf16* g = Whb + (size_t)row * DDIM + k0 + (colb >> 1);
            char* l = &Blds[0][0] + buf * BSZ + (wid * 32 + c * 8) * 128;
            __builtin_amdgcn_global_load_lds((gas_cptr)(const void*)g,
                                             (las_ptr)(void*)l, 16, 0, 0);
        }
    };

    auto stage_write = [&](int buf) {
        bpart += xv.x * wv.x + xv.y * wv.y + xv.z * wv.z + xv.w * wv.w;
        bf16x4 av;
        av[0] = (__bf16)xv.x; av[1] = (__bf16)xv.y;
        av[2] = (__bf16)xv.z; av[3] = (__bf16)xv.w;
        *reinterpret_cast<bf16x4*>(a_dst0 + buf * ASZ) = av;
    };

    auto compute = [&](int buf) {
        const char* Ab = &Alds[0][0] + buf * ASZ;
        const char* Bb = &Blds[0][0] + buf * BSZ;
#pragma unroll
        for (int h = 0; h < 2; ++h) {
            const int slot = (h * 4 + (lane >> 4)) * 16;
            bf16x8 af[2];
#pragma unroll
            for (int rt = 0; rt < 2; ++rt) {
                const int row = wm * 32 + rt * 16 + (lane & 15);
                af[rt] = *reinterpret_cast<const bf16x8*>(Ab + row * 128 + (slot ^ swz(row)));
            }
#pragma unroll
            for (int n = 0; n < 4; ++n) {
                const int trow = wn * 64 + n * 16 + (lane & 15);
                const bf16x8 bfr = *reinterpret_cast<const bf16x8*>(
                    Bb + trow * 128 + (slot ^ swz(trow)));
                acc[0][n] = __builtin_amdgcn_mfma_f32_16x16x32_bf16(af[0], bfr, acc[0][n], 0, 0, 0);
                acc[1][n] = __builtin_amdgcn_mfma_f32_16x16x32_bf16(af[1], bfr, acc[1][n], 0, 0, 0);
            }
        }
    };

    // --- pipelined K loop: counted vmcnt, DMA stays in flight across barriers ---
    stage_issue(0, 0);
    stage_write(0);                 // backend waits xv/wv (vmcnt(4)), B(0) still flying
    for (int it = 0; it < NKIT - 1; ++it) {
        const int cur = it & 1;
        const int nxt = cur ^ 1;
        stage_issue(nxt, it + 1);   // +6 vm ops
        WAIT_TOP();                 // drain everything older than this iter's 6:
        SBAR();                     //   B[cur] DMA complete; A[cur] ds_writes visible
        compute(cur);
        stage_write(nxt);           // backend-inserted vmcnt wait for xv/wv
        WAIT_LGKM();                // ds_write A[nxt] + compute's ds_reads drained
        SBAR();                     // safe: next iter's DMA may overwrite buf cur
    }
    WAIT_VM0();                     // last tile's B DMA
    SBAR();
    compute((NKIT - 1) & 1);

    // --- base = x@Wb + bb : reduce 16 chunk-partials per row ---
    bpart += __shfl_xor(bpart, 1, 16);
    bpart += __shfl_xor(bpart, 2, 16);
    bpart += __shfl_xor(bpart, 4, 16);
    bpart += __shfl_xor(bpart, 8, 16);
    if ((tid & 15) == 0) baseLds[tid >> 4] = bpart + bb0;

    // --- epilogue: bias + relu + in-register inclusive scan over T ---
    // C layout: col(T) = lane&15, row(M) = (lane>>4)*4 + j within 16x16 tile
    float bhv[4];
#pragma unroll
    for (int n = 0; n < 4; ++n)
        bhv[n] = bh[wn * 64 + n * 16 + (lane & 15)];

    float carry[2][4] = {{0.f,0.f,0.f,0.f},{0.f,0.f,0.f,0.f}};
#pragma unroll
    for (int n = 0; n < 4; ++n) {
#pragma unroll
        for (int rt = 0; rt < 2; ++rt) {
#pragma unroll
            for (int j = 0; j < 4; ++j) {
                float v = fmaxf(acc[rt][n][j] + bhv[n], 0.f);
#pragma unroll
                for (int off = 1; off < 16; off <<= 1) {
                    const float u = __shfl_up(v, (unsigned)off, 16);
                    if ((lane & 15) >= off) v += u;
                }
                v += carry[rt][j];
                carry[rt][j] = __shfl(v, 15, 16);
                acc[rt][n][j] = v;
            }
        }
    }

    // per-row 64-col chunk totals -> LDS for cross-wave carry
    if ((lane & 15) == 0) {
#pragma unroll
        for (int rt = 0; rt < 2; ++rt)
#pragma unroll
            for (int j = 0; j < 4; ++j) {
                const int r = wm * 32 + rt * 16 + (lane >> 4) * 4 + j;
                totLds[r][wn] = carry[rt][j];
            }
    }
    __syncthreads();

#pragma unroll
    for (int rt = 0; rt < 2; ++rt) {
#pragma unroll
        for (int j = 0; j < 4; ++j) {
            const int r = wm * 32 + rt * 16 + (lane >> 4) * 4 + j;
            float rc = baseLds[r];
#pragma unroll
            for (int w = 0; w < 7; ++w)
                if (w < wn) rc += totLds[r][w];
            float* orow = out + (size_t)(brow + r) * TDIM + wn * 64 + (lane & 15);
#pragma unroll
            for (int n = 0; n < 4; ++n)
                orow[n * 16] = acc[rt][n][j] + rc;
        }
    }
}

extern "C" void kernel_launch(void* const* d_in, const int* in_sizes, int n_in,
                              void* d_out, int out_size, void* d_ws, size_t ws_size,
                              hipStream_t stream) {
    const float* x  = (const float*)d_in[0];
    const float* Wh = (const float*)d_in[1];
    const float* bh = (const float*)d_in[2];
    const float* Wb = (const float*)d_in[3];
    const float* bb = (const float*)d_in[4];
    float* out = (float*)d_out;
    __bf16* Whb = (__bf16*)d_ws;              // 1 MB scratch

    cvt_wh_kernel<<<512, 256, 0, stream>>>(Wh, Whb);
    survival_kernel<<<256, 1024, 0, stream>>>(x, Whb, bh, Wb, bb, out);
}